// Round 11
// baseline (2221.619 us; speedup 1.0000x reference)
//
#include <hip/hip_runtime.h>
#include <math.h>

#define NN 50000
#define NE 800000
#define FIN 197
#define KIN 224          // FIN zero-padded to multiple of 32
#define H 256
#define HEADS 8
#define HD 32
#define LAYERS 5
#define FF 1024
#define INV_SCALE 0.17677669529663687f   // 1/sqrt(32)

typedef __attribute__((ext_vector_type(8))) short short8;
typedef __attribute__((ext_vector_type(4))) float f32x4;
typedef unsigned short ushort;

// fast GELU via exp2/rcp (max abs err ~3e-4 vs exact erf form)
__device__ __forceinline__ float gelu_f(float x) {
    float x2 = x * x;
    float u = __builtin_fmaf(0.044715f * x2, x, x);
    float e = __builtin_amdgcn_exp2f(-2.3022075f * u);
    return x * __builtin_amdgcn_rcpf(1.0f + e);
}
__device__ __forceinline__ ushort f2b(float f) {        // fp32 -> bf16 RNE
    unsigned u = __float_as_uint(f);
    u += 0x7fffu + ((u >> 16) & 1u);
    return (ushort)(u >> 16);
}
__device__ __forceinline__ float b2f(ushort b) {
    return __uint_as_float(((unsigned)b) << 16);
}
__device__ __forceinline__ float dot2b(unsigned a, unsigned b) {  // 2 packed bf16 pairs
    float a0 = __uint_as_float(a << 16), a1 = __uint_as_float(a & 0xffff0000u);
    float b0 = __uint_as_float(b << 16), b1 = __uint_as_float(b & 0xffff0000u);
    return a0 * b0 + a1 * b1;
}

// async global->LDS 16B per lane; LDS dest = wave-uniform base + lane*16
__device__ __forceinline__ void load16_lds(const ushort* gp, ushort* lp) {
    __builtin_amdgcn_global_load_lds(
        (const __attribute__((address_space(1))) unsigned int*)gp,
        (__attribute__((address_space(3))) unsigned int*)lp,
        16, 0, 0);
}

// ---------------- MFMA bf16 GEMM: C = act(A @ Bt^T + bias) + res ----------------
// r16 32x64->r20 128x128 tile + chunk-XOR swizzle + 2-phase dbuf + r18
// wide-store epilogue. r19 (counted-vmcnt) null; r20 (+intensity) +1.4% --
// steady-state inner loop is NOT the remaining cost; structural traffic is.
__global__ __launch_bounds__(256) void gemm_bf16_kernel(
    const ushort* __restrict__ A, int lda,
    const ushort* __restrict__ Bt,
    const float* __restrict__ bias,
    const float* __restrict__ res, int ldr,
    float* __restrict__ Cf, ushort* __restrict__ Cb, int ldc,
    int n, int K, int act, int gx)   // gx = N/128 col-tiles
{
    __shared__ ushort As[2][128 * 32];   // 16 KB
    __shared__ ushort Bs[2][128 * 32];   // 16 KB
    int tid = threadIdx.x;
    int lane = tid & 63;
    int wave = tid >> 6;

    // swizzled block mapping: groups of (8 row-tiles x gx col-tiles)
    int tiles_y = (n + 127) >> 7;
    int lin = blockIdx.x;
    int gsz = gx * 8;
    int group = lin / gsz;
    int rem = lin - group * gsz;
    int rows_left = tiles_y - group * 8;
    int rg = rows_left < 8 ? rows_left : 8;
    int r = rem % rg;
    int c = rem / rg;
    int brow = (group * 8 + r) * 128;
    int bcol = c * 128;

    f32x4 acc[2][8] = {};
    int m0 = lane & 15;
    int rdc = ((lane >> 4) ^ ((lane >> 1) & 3)) * 8;

    int rA = lane >> 2;
    int c8s = (((lane & 3) ^ ((lane >> 3) & 3)) * 8);

    long arow0, arow1, brow0, brow1;
    {
        int gr0 = brow + wave * 32 + rA;        if (gr0 >= n) gr0 = n - 1;
        int gr1 = brow + wave * 32 + 16 + rA;   if (gr1 >= n) gr1 = n - 1;
        arow0 = (long)gr0 * lda;
        arow1 = (long)gr1 * lda;
        brow0 = (long)(bcol + wave * 32 + rA) * K;
        brow1 = (long)(bcol + wave * 32 + 16 + rA) * K;
    }
    int lo0 = (wave * 32) * 32;
    int lo1 = (wave * 32 + 16) * 32;

    int nt = K >> 5;
    load16_lds(A + arow0 + c8s, &As[0][lo0]);
    load16_lds(A + arow1 + c8s, &As[0][lo1]);
    load16_lds(Bt + brow0 + c8s, &Bs[0][lo0]);
    load16_lds(Bt + brow1 + c8s, &Bs[0][lo1]);
    __syncthreads();

    for (int t = 0; t < nt; ++t) {
        int p = t & 1;
        if (t + 1 < nt) {                 // prefetch next K-tile into other buffer
            int k0 = (t + 1) << 5;
            load16_lds(A + arow0 + k0 + c8s, &As[p ^ 1][lo0]);
            load16_lds(A + arow1 + k0 + c8s, &As[p ^ 1][lo1]);
            load16_lds(Bt + brow0 + k0 + c8s, &Bs[p ^ 1][lo0]);
            load16_lds(Bt + brow1 + k0 + c8s, &Bs[p ^ 1][lo1]);
        }
        short8 af[2], bfr[8];
        #pragma unroll
        for (int i = 0; i < 2; ++i)
            af[i] = *(const short8*)&As[p][(wave * 32 + i * 16 + m0) * 32 + rdc];
        #pragma unroll
        for (int j = 0; j < 8; ++j)
            bfr[j] = *(const short8*)&Bs[p][(j * 16 + m0) * 32 + rdc];
        #pragma unroll
        for (int i = 0; i < 2; ++i)
            #pragma unroll
            for (int j = 0; j < 8; ++j)
                acc[i][j] = __builtin_amdgcn_mfma_f32_16x16x32_bf16(af[i], bfr[j], acc[i][j], 0, 0, 0);
        __syncthreads();                  // next buffer staged (drains vmcnt)
    }

    // ---- wide-store epilogue: 8KB/wave staging from the 4 idle buffer slices ----
    float* ch0 = (float*)&As[0][wave * 1024];
    float* ch1 = (float*)&As[1][wave * 1024];
    float* ch2 = (float*)&Bs[0][wave * 1024];
    float* ch3 = (float*)&Bs[1][wave * 1024];
    int ccol = lane & 15;
    int mych = lane >> 4;                       // crow0 = mych*4 -> chunk = mych
    float* wch = (mych == 0) ? ch0 : ((mych == 1) ? ch1 : ((mych == 2) ? ch2 : ch3));
    int gcol = bcol + (lane & 31) * 4;
    #pragma unroll
    for (int i = 0; i < 2; ++i) {
        int rowbase = brow + wave * 32 + i * 16;
        #pragma unroll
        for (int rr = 0; rr < 4; ++rr)
            #pragma unroll
            for (int j = 0; j < 8; ++j)
                wch[rr * 128 + j * 16 + ccol] = acc[i][j][rr];
        // same-wave LDS write->read ordering; compiler inserts lgkmcnt.
        #pragma unroll
        for (int k = 0; k < 8; ++k) {
            const float* rch = ((k >> 1) == 0) ? ch0 :
                               (((k >> 1) == 1) ? ch1 :
                               (((k >> 1) == 2) ? ch2 : ch3));   // compile-time
            f32x4 v = *(const f32x4*)&rch[(((k & 1) * 64) + lane) * 4];
            int grow = rowbase + 2 * k + (lane >> 5);
            if (bias) {
                float4 b4 = *(const float4*)(bias + gcol);
                v[0] += b4.x; v[1] += b4.y; v[2] += b4.z; v[3] += b4.w;
            }
            if (act) {
                v[0] = gelu_f(v[0]); v[1] = gelu_f(v[1]);
                v[2] = gelu_f(v[2]); v[3] = gelu_f(v[3]);
            }
            if (grow < n) {
                if (res) {
                    float4 r4 = *(const float4*)(res + (long)grow * ldr + gcol);
                    v[0] += r4.x; v[1] += r4.y; v[2] += r4.z; v[3] += r4.w;
                }
                if (Cf) *(f32x4*)(Cf + (long)grow * ldc + gcol) = v;
                if (Cb) {
                    ushort4 ob = { f2b(v[0]), f2b(v[1]), f2b(v[2]), f2b(v[3]) };
                    *(ushort4*)(Cb + (long)grow * ldc + gcol) = ob;
                }
            }
        }
        // no barrier needed between passes: slices are wave-private
    }
}

// ---------------- fused GEMM(256-col) + bias + residual(B0) + LayerNorm ----------------
// Round-21. r19 null + r20 +1.4% => GEMM inner loop is not the remaining
// cost; ROUND-TRIP TRAFFIC is (~515MB): woo write+read (51.2MB/l), ln2
// (154MB/l), ln1 (77MB/l), l=4 dead B0 write. This kernel fuses
// GEMM -> +bias -> +B0 residual -> LN -> {B0, hb} for all 256-col GEMMs
// (Wo and FFN2). Wave-tile 16x256 (acc[16]=64 AGPR): each wave owns FULL
// rows, so LN is entirely in-wave (sum over j-regs + 4 shfl_xor in the
// 16-lane group) -- no slab staging, no extra barriers. Same fp32 math as
// the separate kernels (strictly less rounding: woo no longer bf16'd).
// Flags: do_ln (l=4 FFN2 skips), ln_to_b0 (Wo: B0=LN out; FFN2: B0=pre-LN),
// write_b0 (l=4: B0 dead, skip 51.2MB).
__global__ __launch_bounds__(256) void gemm_ln_kernel(
    const ushort* __restrict__ A, int K,          // lda == K
    const ushort* __restrict__ Bt,                // [256][K] bf16
    const float* __restrict__ bias,               // [256]
    float* __restrict__ B0,                       // residual in / out (fp32 NxH)
    const float* __restrict__ g, const float* __restrict__ bta,
    ushort* __restrict__ hb, int n,
    int do_ln, int ln_to_b0, int write_b0)
{
    __shared__ ushort As[2][64 * 32];    // 8 KB
    __shared__ ushort Bs[2][256 * 32];   // 32 KB
    int tid = threadIdx.x;
    int lane = tid & 63;
    int wave = tid >> 6;                 // 0..3
    int brow = blockIdx.x * 64;
    int wrow = brow + wave * 16;         // this wave's 16 output rows

    f32x4 acc[16] = {};
    int m0 = lane & 15;
    int rdc = ((lane >> 4) ^ ((lane >> 1) & 3)) * 8;      // read swizzle
    int rA = lane >> 2;
    int c8s = (((lane & 3) ^ ((lane >> 3) & 3)) * 8);     // staging src chunk

    long arow;
    { int gr = wrow + rA; if (gr >= n) gr = n - 1; arow = (long)gr * K; }
    long brow0 = (long)(wave * 64 + rA) * K;              // B rows wave*64..+64
    int loA = (wave * 16) * 32;
    int loB = (wave * 64) * 32;

    int nt = K >> 5;
    load16_lds(A + arow + c8s, &As[0][loA]);
    #pragma unroll
    for (int q = 0; q < 4; ++q)
        load16_lds(Bt + brow0 + (long)q * 16 * K + c8s, &Bs[0][loB + q * 16 * 32]);
    __syncthreads();

    for (int t = 0; t < nt; ++t) {
        int p = t & 1;
        if (t + 1 < nt) {
            int k0 = (t + 1) << 5;
            load16_lds(A + arow + k0 + c8s, &As[p ^ 1][loA]);
            #pragma unroll
            for (int q = 0; q < 4; ++q)
                load16_lds(Bt + brow0 + (long)q * 16 * K + k0 + c8s,
                           &Bs[p ^ 1][loB + q * 16 * 32]);
        }
        short8 af = *(const short8*)&As[p][(wave * 16 + m0) * 32 + rdc];
        #pragma unroll
        for (int jg = 0; jg < 4; ++jg) {          // groups of 4 to limit live regs
            short8 b0r = *(const short8*)&Bs[p][((jg * 64) + m0) * 32 + rdc];
            short8 b1r = *(const short8*)&Bs[p][((jg * 64) + 16 + m0) * 32 + rdc];
            short8 b2r = *(const short8*)&Bs[p][((jg * 64) + 32 + m0) * 32 + rdc];
            short8 b3r = *(const short8*)&Bs[p][((jg * 64) + 48 + m0) * 32 + rdc];
            acc[jg * 4 + 0] = __builtin_amdgcn_mfma_f32_16x16x32_bf16(af, b0r, acc[jg * 4 + 0], 0, 0, 0);
            acc[jg * 4 + 1] = __builtin_amdgcn_mfma_f32_16x16x32_bf16(af, b1r, acc[jg * 4 + 1], 0, 0, 0);
            acc[jg * 4 + 2] = __builtin_amdgcn_mfma_f32_16x16x32_bf16(af, b2r, acc[jg * 4 + 2], 0, 0, 0);
            acc[jg * 4 + 3] = __builtin_amdgcn_mfma_f32_16x16x32_bf16(af, b3r, acc[jg * 4 + 3], 0, 0, 0);
        }
        __syncthreads();
    }

    // ---- fused epilogue: v = acc + bias + B0_old; LN in-wave ----
    int li = lane & 15, lg = lane >> 4;
    // rows handled by this lane: wrow + lg*4 + rr (rr=0..3); cols j*16+li
    #pragma unroll
    for (int j = 0; j < 16; ++j) {
        float bj = bias[j * 16 + li];
        #pragma unroll
        for (int rr = 0; rr < 4; ++rr) {
            int grow = wrow + lg * 4 + rr;
            float rv = (grow < n) ? B0[(long)grow * H + j * 16 + li] : 0.f;
            acc[j][rr] += bj + rv;
        }
    }
    if (do_ln) {
        float s0 = 0.f, s1 = 0.f, s2 = 0.f, s3 = 0.f;
        #pragma unroll
        for (int j = 0; j < 16; ++j) { s0 += acc[j][0]; s1 += acc[j][1]; s2 += acc[j][2]; s3 += acc[j][3]; }
        #pragma unroll
        for (int off = 1; off < 16; off <<= 1) {
            s0 += __shfl_xor(s0, off); s1 += __shfl_xor(s1, off);
            s2 += __shfl_xor(s2, off); s3 += __shfl_xor(s3, off);
        }
        float mn0 = s0 * (1.0f / H), mn1 = s1 * (1.0f / H), mn2 = s2 * (1.0f / H), mn3 = s3 * (1.0f / H);
        float q0 = 0.f, q1 = 0.f, q2 = 0.f, q3 = 0.f;
        #pragma unroll
        for (int j = 0; j < 16; ++j) {
            float d0 = acc[j][0] - mn0, d1 = acc[j][1] - mn1;
            float d2 = acc[j][2] - mn2, d3 = acc[j][3] - mn3;
            q0 += d0 * d0; q1 += d1 * d1; q2 += d2 * d2; q3 += d3 * d3;
        }
        #pragma unroll
        for (int off = 1; off < 16; off <<= 1) {
            q0 += __shfl_xor(q0, off); q1 += __shfl_xor(q1, off);
            q2 += __shfl_xor(q2, off); q3 += __shfl_xor(q3, off);
        }
        float rs0 = rsqrtf(q0 * (1.0f / H) + 1e-5f);
        float rs1 = rsqrtf(q1 * (1.0f / H) + 1e-5f);
        float rs2 = rsqrtf(q2 * (1.0f / H) + 1e-5f);
        float rs3 = rsqrtf(q3 * (1.0f / H) + 1e-5f);
        #pragma unroll
        for (int j = 0; j < 16; ++j) {
            int col = j * 16 + li;
            float gj = g[col], bj = bta[col];
            float o0 = (acc[j][0] - mn0) * rs0 * gj + bj;
            float o1 = (acc[j][1] - mn1) * rs1 * gj + bj;
            float o2 = (acc[j][2] - mn2) * rs2 * gj + bj;
            float o3 = (acc[j][3] - mn3) * rs3 * gj + bj;
            #pragma unroll
            for (int rr = 0; rr < 4; ++rr) {
                int grow = wrow + lg * 4 + rr;
                if (grow >= n) continue;
                float ov = (rr == 0) ? o0 : ((rr == 1) ? o1 : ((rr == 2) ? o2 : o3));
                if (write_b0)
                    B0[(long)grow * H + col] = ln_to_b0 ? ov : acc[j][rr];
                hb[(long)grow * H + col] = f2b(ov);
            }
        }
    } else {
        #pragma unroll
        for (int j = 0; j < 16; ++j) {
            int col = j * 16 + li;
            #pragma unroll
            for (int rr = 0; rr < 4; ++rr) {
                int grow = wrow + lg * 4 + rr;
                if (grow >= n) continue;
                if (write_b0) B0[(long)grow * H + col] = acc[j][rr];
                hb[(long)grow * H + col] = f2b(acc[j][rr]);
            }
        }
    }
}

// ---------------- LayerNorm rows of 256; input fp32 (af) or bf16 (ab) ----------------
__global__ __launch_bounds__(256) void ln256_kernel(
    const float* __restrict__ af, const ushort* __restrict__ ab,
    const float* __restrict__ res,
    const float* __restrict__ g, const float* __restrict__ bta,
    float* __restrict__ outf, ushort* __restrict__ outb, int n, int post_gelu)
{
    int row = blockIdx.x * 4 + (threadIdx.x >> 6);
    if (row >= n) return;
    int lane = threadIdx.x & 63;
    float4 v;
    if (af) {
        v = *(const float4*)(af + (long)row * H + lane * 4);
    } else {
        ushort4 vb = *(const ushort4*)(ab + (long)row * H + lane * 4);
        v.x = b2f(vb.x); v.y = b2f(vb.y); v.z = b2f(vb.z); v.w = b2f(vb.w);
    }
    if (res) {
        float4 r = *(const float4*)(res + (long)row * H + lane * 4);
        v.x += r.x; v.y += r.y; v.z += r.z; v.w += r.w;
    }
    float s = v.x + v.y + v.z + v.w;
    #pragma unroll
    for (int off = 1; off < 64; off <<= 1) s += __shfl_xor(s, off);
    float mean = s * (1.0f / H);
    float dx = v.x - mean, dy = v.y - mean, dz = v.z - mean, dw = v.w - mean;
    float qs = dx * dx + dy * dy + dz * dz + dw * dw;
    #pragma unroll
    for (int off = 1; off < 64; off <<= 1) qs += __shfl_xor(qs, off);
    float rstd = rsqrtf(qs * (1.0f / H) + 1e-5f);
    float4 gg = *(const float4*)(g + lane * 4);
    float4 bb = *(const float4*)(bta + lane * 4);
    float4 o;
    o.x = dx * rstd * gg.x + bb.x;
    o.y = dy * rstd * gg.y + bb.y;
    o.z = dz * rstd * gg.z + bb.z;
    o.w = dw * rstd * gg.w + bb.w;
    if (post_gelu) { o.x = gelu_f(o.x); o.y = gelu_f(o.y); o.z = gelu_f(o.z); o.w = gelu_f(o.w); }
    if (outf) *(float4*)(outf + (long)row * H + lane * 4) = o;
    if (outb) {
        ushort4 ob = { f2b(o.x), f2b(o.y), f2b(o.z), f2b(o.w) };
        *(ushort4*)(outb + (long)row * H + lane * 4) = ob;
    }
}

// ---------------- conversions ----------------
__global__ __launch_bounds__(256) void xcast_kernel(const float* __restrict__ x,
                                                    ushort* __restrict__ xb)
{
    long i = (long)blockIdx.x * 256 + threadIdx.x;
    if (i >= (long)NN * KIN) return;
    int n = (int)(i / KIN), c = (int)(i % KIN);
    xb[i] = (c < FIN) ? f2b(x[(long)n * FIN + c]) : (ushort)0;
}

__global__ __launch_bounds__(256) void wtin_kernel(const float* __restrict__ W,
                                                   ushort* __restrict__ Wt)
{
    int i = blockIdx.x * 256 + threadIdx.x;
    if (i >= 256 * KIN) return;
    int m = i / KIN, k = i % KIN;
    Wt[i] = (k < FIN) ? f2b(W[(long)k * H + m]) : (ushort)0;
}

__global__ __launch_bounds__(256) void wtqkv_kernel(
    const float* __restrict__ Wq, const float* __restrict__ Wk,
    const float* __restrict__ Wv, ushort* __restrict__ out)
{
    long i = (long)blockIdx.x * 256 + threadIdx.x;
    if (i >= (long)LAYERS * 768 * 256) return;
    int l = (int)(i / (768 * 256));
    int r = (int)(i % (768 * 256));
    int m = r >> 8, k = r & 255;
    const float* W = (m < 256) ? Wq : ((m < 512) ? Wk : Wv);
    out[i] = f2b(W[(long)l * 65536 + (long)k * 256 + (m & 255)]);
}

__global__ __launch_bounds__(256) void wtgen_kernel(
    const float* __restrict__ W, ushort* __restrict__ out, int L, int K, int M)
{
    long i = (long)blockIdx.x * 256 + threadIdx.x;
    if (i >= (long)L * K * M) return;
    int l = (int)(i / ((long)K * M));
    int r = (int)(i % ((long)K * M));
    int m = r / K, k = r % K;
    out[i] = f2b(W[(long)l * K * M + (long)k * M + m]);
}

// ---------------- CSR build ----------------
__global__ __launch_bounds__(256) void deg_kernel(const int* __restrict__ dst,
                                                   int* __restrict__ deg)
{
    int e = blockIdx.x * 256 + threadIdx.x;
    if (e >= NE) return;
    atomicAdd(&deg[dst[e]], 1);
}

__global__ __launch_bounds__(256) void scan1_kernel(const int* __restrict__ deg,
                                                     int* __restrict__ rowptr,
                                                     int* __restrict__ bsum)
{
    __shared__ int buf[256];
    int tid = threadIdx.x;
    int i = blockIdx.x * 256 + tid;
    int v = (i < NN) ? deg[i] : 0;
    buf[tid] = v;
    __syncthreads();
    #pragma unroll
    for (int off = 1; off < 256; off <<= 1) {
        int t = (tid >= off) ? buf[tid - off] : 0;
        __syncthreads();
        buf[tid] += t;
        __syncthreads();
    }
    if (i < NN) rowptr[i] = buf[tid] - v;
    if (tid == 255) bsum[blockIdx.x] = buf[255];
}

__global__ __launch_bounds__(256) void scan2_kernel(int* __restrict__ bsum, int nb)
{
    __shared__ int buf[256];
    int tid = threadIdx.x;
    int v = (tid < nb) ? bsum[tid] : 0;
    buf[tid] = v;
    __syncthreads();
    #pragma unroll
    for (int off = 1; off < 256; off <<= 1) {
        int t = (tid >= off) ? buf[tid - off] : 0;
        __syncthreads();
        buf[tid] += t;
        __syncthreads();
    }
    if (tid < nb) bsum[tid] = buf[tid] - v;
}

__global__ __launch_bounds__(256) void scan3_kernel(int* __restrict__ rowptr,
                                                     const int* __restrict__ bsum)
{
    int i = blockIdx.x * 256 + threadIdx.x;
    if (i < NN) rowptr[i] += bsum[blockIdx.x];
    if (i == 0) rowptr[NN] = NE;
}

__global__ __launch_bounds__(256) void fill_kernel(
    const int* __restrict__ src, const int* __restrict__ dst,
    const float* __restrict__ ea, const int* __restrict__ rowptr,
    int* __restrict__ cursor, int* __restrict__ csr_src,
    float2* __restrict__ csr_ea)
{
    int e = blockIdx.x * 256 + threadIdx.x;
    if (e >= NE) return;
    int d = dst[e];
    int pos = atomicAdd(&cursor[d], 1);
    int j = rowptr[d] + pos;
    csr_src[j] = src[e];
    csr_ea[j] = *(const float2*)(ea + 2 * e);
}

// ---------------- fused gather attention (one wave per node, all 8 heads) ----------------
// Depth-4 register prefetch, pairwise softmax, exp2-domain. Pinned at the
// random-gather L2-fill ceiling (~3.4 TB/s, FETCH 392MB constant across
// depth-2/depth-4/sorted variants). fp8 K/V byte-reduction REJECTED by error
// arithmetic: e4m3 ~6% relative -> aggb err ~0.06 absolute > entire current
// absmax (0.0469). 635us total is this algorithm's floor.
#define LOADE(idx, kbuf, vbuf, ebuf)                                   \
    { int s_ = csr_src[idx]; ebuf = csr_ea[idx];                       \
      const ushort* kr_ = qkv + (long)s_ * 768 + 256;                  \
      kbuf = *(const uint2*)(kr_ + lane * 4);                          \
      vbuf = *(const uint2*)(kr_ + 256 + lane * 4); }

#define PAIR(k1, v1, e1, k2, v2, e2)                                               \
    { float p1 = dot2b(q2.x, (k1).x) + dot2b(q2.y, (k1).y);                        \
      float p2 = dot2b(q2.x, (k2).x) + dot2b(q2.y, (k2).y);                        \
      p1 += __shfl_xor(p1, 1);  p2 += __shfl_xor(p2, 1);                           \
      p1 += __shfl_xor(p1, 2);  p2 += __shfl_xor(p2, 2);                           \
      p1 += __shfl_xor(p1, 4);  p2 += __shfl_xor(p2, 4);                           \
      float s1 = p1 * c1 + (e1).x * w0 + (e1).y * w1 + bb;                         \
      float s2 = p2 * c1 + (e2).x * w0 + (e2).y * w1 + bb;                         \
      float mp = fmaxf(s1, s2);                                                    \
      float x1 = __builtin_amdgcn_exp2f(s1 - mp);                                  \
      float x2 = __builtin_amdgcn_exp2f(s2 - mp);                                  \
      float lp = x1 + x2;                                                          \
      float b0 = x1 * __uint_as_float((v1).x << 16)         + x2 * __uint_as_float((v2).x << 16);          \
      float b1 = x1 * __uint_as_float((v1).x & 0xffff0000u) + x2 * __uint_as_float((v2).x & 0xffff0000u);  \
      float b2 = x1 * __uint_as_float((v1).y << 16)         + x2 * __uint_as_float((v2).y << 16);          \
      float b3 = x1 * __uint_as_float((v1).y & 0xffff0000u) + x2 * __uint_as_float((v2).y & 0xffff0000u);  \
      float mn = fmaxf(m, mp);                                                     \
      float so = __builtin_amdgcn_exp2f(m - mn);                                   \
      float sp = __builtin_amdgcn_exp2f(mp - mn);                                  \
      l  = l  * so + lp * sp;                                                      \
      a0 = a0 * so + b0 * sp;                                                      \
      a1 = a1 * so + b1 * sp;                                                      \
      a2 = a2 * so + b2 * sp;                                                      \
      a3 = a3 * so + b3 * sp;                                                      \
      m = mn; }

#define SINGLE(kb, vb, eb)                                                         \
    { float p1 = dot2b(q2.x, (kb).x) + dot2b(q2.y, (kb).y);                        \
      p1 += __shfl_xor(p1, 1);                                                     \
      p1 += __shfl_xor(p1, 2);                                                     \
      p1 += __shfl_xor(p1, 4);                                                     \
      float s1 = p1 * c1 + (eb).x * w0 + (eb).y * w1 + bb;                         \
      float mn = fmaxf(m, s1);                                                     \
      float so = __builtin_amdgcn_exp2f(m - mn);                                   \
      float e_ = __builtin_amdgcn_exp2f(s1 - mn);                                  \
      l  = l  * so + e_;                                                           \
      a0 = a0 * so + e_ * __uint_as_float((vb).x << 16);                           \
      a1 = a1 * so + e_ * __uint_as_float((vb).x & 0xffff0000u);                   \
      a2 = a2 * so + e_ * __uint_as_float((vb).y << 16);                           \
      a3 = a3 * so + e_ * __uint_as_float((vb).y & 0xffff0000u);                   \
      m = mn; }

__global__ __launch_bounds__(256) void attn_kernel(
    const ushort* __restrict__ qkv,
    const int* __restrict__ rowptr, const int* __restrict__ csr_src,
    const float2* __restrict__ csr_ea,
    const float* __restrict__ We, const float* __restrict__ be,
    ushort* __restrict__ aggb)
{
    int node = blockIdx.x * 4 + (threadIdx.x >> 6);
    if (node >= NN) return;
    int lane = threadIdx.x & 63;
    int h = lane >> 3;                 // global head 0..7
    const float L2E = 1.4426950408889634f;
    float w0 = We[h] * L2E, w1 = We[8 + h] * L2E, bb = be[h] * L2E;
    const float c1 = INV_SCALE * L2E;

    uint2 q2 = *(const uint2*)(qkv + (long)node * 768 + lane * 4);
    int jbeg = rowptr[node], jend = rowptr[node + 1];

    float m = -1e30f, l = 0.f;
    float a0 = 0.f, a1 = 0.f, a2 = 0.f, a3 = 0.f;

    uint2 k0v = {0,0}, v0v = {0,0}, k1v = {0,0}, v1v = {0,0};
    uint2 k2v = {0,0}, v2v = {0,0}, k3v = {0,0}, v3v = {0,0};
    float2 e0v = {0.f,0.f}, e1v = {0.f,0.f}, e2v = {0.f,0.f}, e3v = {0.f,0.f};

    if (jbeg + 0 < jend) LOADE(jbeg + 0, k0v, v0v, e0v);
    if (jbeg + 1 < jend) LOADE(jbeg + 1, k1v, v1v, e1v);
    if (jbeg + 2 < jend) LOADE(jbeg + 2, k2v, v2v, e2v);
    if (jbeg + 3 < jend) LOADE(jbeg + 3, k3v, v3v, e3v);

    int j = jbeg;
    for (; j + 3 < jend; j += 4) {
        PAIR(k0v, v0v, e0v, k1v, v1v, e1v);          // edges j, j+1
        if (j + 4 < jend) LOADE(j + 4, k0v, v0v, e0v);
        if (j + 5 < jend) LOADE(j + 5, k1v, v1v, e1v);
        PAIR(k2v, v2v, e2v, k3v, v3v, e3v);          // edges j+2, j+3
        if (j + 6 < jend) LOADE(j + 6, k2v, v2v, e2v);
        if (j + 7 < jend) LOADE(j + 7, k3v, v3v, e3v);
    }
    int rleft = jend - j;                            // 0..3
    if (rleft >= 2) PAIR(k0v, v0v, e0v, k1v, v1v, e1v);
    if (rleft == 3) SINGLE(k2v, v2v, e2v);
    if (rleft == 1) SINGLE(k0v, v0v, e0v);

    float inv = 1.0f / (l + 1e-16f);
    ushort4 o = { f2b(a0 * inv), f2b(a1 * inv), f2b(a2 * inv), f2b(a3 * inv) };
    *(ushort4*)(aggb + (long)node * 256 + lane * 4) = o;
}

// ---------------- classifier tail ----------------
__global__ __launch_bounds__(256) void cls_kernel(
    const float* __restrict__ t1, const float* __restrict__ W,
    const float* __restrict__ b, float* __restrict__ out)
{
    int i = blockIdx.x * 256 + threadIdx.x;
    if (i >= NN) return;
    const float* tp = t1 + (long)i * 128;
    float a0 = 0.f, a1 = 0.f;
    #pragma unroll
    for (int j = 0; j < 128; j += 4) {
        float4 t = *(const float4*)(tp + j);
        a0 += t.x * W[(j + 0) * 2] + t.y * W[(j + 1) * 2] + t.z * W[(j + 2) * 2] + t.w * W[(j + 3) * 2];
        a1 += t.x * W[(j + 0) * 2 + 1] + t.y * W[(j + 1) * 2 + 1] + t.z * W[(j + 2) * 2 + 1] + t.w * W[(j + 3) * 2 + 1];
    }
    float l0 = a0 + b[0], l1 = a1 + b[1];
    out[(long)i * 2 + 0] = l0;
    out[(long)i * 2 + 1] = l1;
    float mx = fmaxf(l0, l1);
    float p0 = expf(l0 - mx), p1 = expf(l1 - mx);
    float sden = p0 + p1;
    out[2L * NN + (long)i * 2 + 0] = p0 / sden;
    out[2L * NN + (long)i * 2 + 1] = p1 / sden;
}

extern "C" void kernel_launch(void* const* d_in, const int* in_sizes, int n_in,
                              void* d_out, int out_size, void* d_ws, size_t ws_size,
                              hipStream_t stream) {
    const float* x      = (const float*)d_in[0];
    const int*   ei     = (const int*)d_in[1];
    const float* ea     = (const float*)d_in[2];
    const float* in_W   = (const float*)d_in[3];
    const float* in_b   = (const float*)d_in[4];
    const float* in_g   = (const float*)d_in[5];
    const float* in_bb  = (const float*)d_in[6];
    const float* Wq     = (const float*)d_in[7];
    const float* Wk     = (const float*)d_in[8];
    const float* Wv     = (const float*)d_in[9];
    const float* We     = (const float*)d_in[10];
    const float* be     = (const float*)d_in[11];
    const float* Wo     = (const float*)d_in[12];
    const float* bo     = (const float*)d_in[13];
    const float* ln1_g  = (const float*)d_in[14];
    const float* ln1_b  = (const float*)d_in[15];
    const float* ln2_g  = (const float*)d_in[16];
    const float* ln2_b  = (const float*)d_in[17];
    const float* f1_W   = (const float*)d_in[18];
    const float* f1_b   = (const float*)d_in[19];
    const float* f2_W   = (const float*)d_in[20];
    const float* f2_b   = (const float*)d_in[21];
    const float* cls1_W = (const float*)d_in[22];
    const float* cls1_b = (const float*)d_in[23];
    const float* cls2_W = (const float*)d_in[24];
    const float* cls2_b = (const float*)d_in[25];
    float* out = (float*)d_out;

    const int* src = ei;
    const int* dst = ei + NE;

    // ---- workspace layout (~197 MB) ----
    char* w = (char*)d_ws;
    float* B0 = (float*)w;            w += (size_t)NN * H * 4;       // h / out (fp32)
    ushort* hb = (ushort*)w;          w += (size_t)NN * H * 2;       // bf16 activations
    char* pool = w;                   w += (size_t)NN * 1024 * 2;    // 102.4 MB union
    ushort* qkv  = (ushort*)pool;                                    // N x 768 bf16
    ushort* aggb = (ushort*)(pool + (size_t)NN * 768 * 2);           // N x 256 bf16
    float*  tproj = (float*)pool;                                    // input-proj t
    ushort* xb   = (ushort*)(pool + (size_t)NN * H * 4);             // N x 224 bf16
    ushort* tb   = (ushort*)pool;                                    // FFN N x 1024 bf16
    float*  t1   = (float*)pool;                                     // cls hidden fp32
    int* deg    = (int*)w;            w += (size_t)NN * 4;
    int* cursor = (int*)w;            w += (size_t)NN * 4;
    int* rowptr = (int*)w;            w += (size_t)(NN + 2) * 4;
    int* bsum   = (int*)w;            w += 1024;
    int* csr_src = (int*)w;           w += (size_t)NE * 4;
    float2* csr_ea = (float2*)w;      w += (size_t)NE * 8;
    ushort* wqkv_t = (ushort*)w;      w += (size_t)LAYERS * 768 * 256 * 2;
    ushort* wo_t  = (ushort*)w;       w += (size_t)LAYERS * 65536 * 2;
    ushort* f1_t  = (ushort*)w;       w += (size_t)LAYERS * 262144 * 2;
    ushort* f2_t  = (ushort*)w;       w += (size_t)LAYERS * 262144 * 2;
    ushort* c1_t  = (ushort*)w;       w += (size_t)32768 * 2;
    ushort* inw_t = (ushort*)w;       w += (size_t)256 * KIN * 2;

    dim3 blk(256);
    const int ln_grid = (NN + 3) / 4;
    const int e_grid = (NE + 255) / 256;
    const int n_grid = (NN + 255) / 256;
    const int ty = (NN + 127) / 128;   // 128-row tiles
    const int ty2 = (NN + 63) / 64;    // 64-row tiles (fused GEMM+LN)

    // ---- CSR build ----
    hipMemsetAsync(deg, 0, (size_t)NN * 4, stream);
    hipMemsetAsync(cursor, 0, (size_t)NN * 4, stream);
    deg_kernel<<<e_grid, blk, 0, stream>>>(dst, deg);
    scan1_kernel<<<n_grid, blk, 0, stream>>>(deg, rowptr, bsum);
    scan2_kernel<<<1, blk, 0, stream>>>(bsum, n_grid);
    scan3_kernel<<<n_grid, blk, 0, stream>>>(rowptr, bsum);
    fill_kernel<<<e_grid, blk, 0, stream>>>(src, dst, ea, rowptr, cursor, csr_src, csr_ea);

    // ---- weight convert/transpose ----
    wtqkv_kernel<<<(int)(((long)LAYERS * 768 * 256 + 255) / 256), blk, 0, stream>>>(Wq, Wk, Wv, wqkv_t);
    wtgen_kernel<<<(int)(((long)LAYERS * 65536 + 255) / 256), blk, 0, stream>>>(Wo, wo_t, LAYERS, 256, 256);
    wtgen_kernel<<<(int)(((long)LAYERS * 262144 + 255) / 256), blk, 0, stream>>>(f1_W, f1_t, LAYERS, 256, 1024);
    wtgen_kernel<<<(int)(((long)LAYERS * 262144 + 255) / 256), blk, 0, stream>>>(f2_W, f2_t, LAYERS, 1024, 256);
    wtgen_kernel<<<(32768 + 255) / 256, blk, 0, stream>>>(cls1_W, c1_t, 1, 256, 128);
    wtin_kernel<<<(256 * KIN + 255) / 256, blk, 0, stream>>>(in_W, inw_t);

    // ---- input projection (MFMA) ----
    xcast_kernel<<<(int)(((long)NN * KIN + 255) / 256), blk, 0, stream>>>(x, xb);
    {
        gemm_bf16_kernel<<<2 * ty, blk, 0, stream>>>(xb, KIN, inw_t, in_b, nullptr, 0,
                                                     tproj, nullptr, H, NN, KIN, 0, 2);
        ln256_kernel<<<ln_grid, blk, 0, stream>>>(tproj, nullptr, nullptr, in_g, in_bb, B0, nullptr, NN, 1);
    }

    // layer-0 LN1 (subsequent LN1s are fused into the previous layer's FFN2)
    ln256_kernel<<<ln_grid, blk, 0, stream>>>(B0, nullptr, nullptr, ln1_g, ln1_b, nullptr, hb, NN, 0);

    for (int l = 0; l < LAYERS; ++l) {
        const float* we  = We + (long)l * 16;
        const float* bel = be + (long)l * 8;
        const float* bol = bo + (long)l * H;
        const float* g2 = ln2_g + (long)l * H;
        const float* b2 = ln2_b + (long)l * H;
        const float* bf1 = f1_b + (long)l * FF;
        const float* bf2 = f2_b + (long)l * H;

        // fused QKV (M=768) + 8-head gather attention
        gemm_bf16_kernel<<<6 * ty, blk, 0, stream>>>(hb, H, wqkv_t + (long)l * 768 * 256,
            nullptr, nullptr, 0, nullptr, qkv, 768, NN, H, 0, 6);
        attn_kernel<<<(NN + 3) / 4, blk, 0, stream>>>(qkv, rowptr, csr_src, csr_ea, we, bel, aggb);

        // fused Wo + bias + residual(B0) + LN2 -> B0 (LN out), hb
        gemm_ln_kernel<<<ty2, blk, 0, stream>>>(aggb, H, wo_t + (long)l * 65536,
            bol, B0, g2, b2, hb, NN, 1, 1, 1);

        // FFN1: tb = gelu(hb@f1^T + bf1) bf16
        gemm_bf16_kernel<<<8 * ty, blk, 0, stream>>>(hb, H, f1_t + (long)l * 262144,
            bf1, nullptr, 0, nullptr, tb, FF, NN, H, 1, 8);

        // fused FFN2 + bias + residual(B0) [+ LN1 of next layer]
        if (l + 1 < LAYERS) {
            gemm_ln_kernel<<<ty2, blk, 0, stream>>>(tb, FF, f2_t + (long)l * 262144,
                bf2, B0, ln1_g + (long)(l + 1) * H, ln1_b + (long)(l + 1) * H,
                hb, NN, 1, 0, 1);      // B0 = pre-LN residual; hb = LN1_{l+1}
        } else {
            gemm_ln_kernel<<<ty2, blk, 0, stream>>>(tb, FF, f2_t + (long)l * 262144,
                bf2, B0, nullptr, nullptr, hb, NN, 0, 0, 0);  // hb = bf16(h_final)
        }
    }

    // ---- classifier ----
    {
        gemm_bf16_kernel<<<1 * ty, blk, 0, stream>>>(hb, H, c1_t, cls1_b, nullptr, 0,
                                                     t1, nullptr, 128, NN, H, 1, 1);
        cls_kernel<<<n_grid, blk, 0, stream>>>(t1, cls2_W, cls2_b, out);
    }
}